// Round 1
// baseline (513.774 us; speedup 1.0000x reference)
//
#include <hip/hip_runtime.h>

// MeshLaplacianLoss: mean |lap(v1) - lap(v2)| over (B=4, N=100000, 3).
// Key identity: lap is linear in verts with faces fixed, so
//   lap1 - lap2 = segsum(d[src])/deg - d   with d = v1 - v2.
// One scatter pass over the difference instead of two Laplacians.

constexpr int NPOINT = 100000;
constexpr int NFACES = 200000;
constexpr int BATCH  = 4;

// ---------------------------------------------------------------- diff ----
__global__ void diff_kernel(const float* __restrict__ v1,
                            const float* __restrict__ v2,
                            float* __restrict__ d, int n) {
    int idx    = blockIdx.x * blockDim.x + threadIdx.x;
    int stride = gridDim.x * blockDim.x;
    for (int i = idx; i < n; i += stride) d[i] = v1[i] - v2[i];
}

// ------------------------------------------------------------- scatter ----
// One thread per face. tgt=[i,i,j,j,k,k], src=[j,k,i,k,i,j] means:
//   nn[i] += d[j]+d[k]; nn[j] += d[i]+d[k]; nn[k] += d[i]+d[j];
//   deg[i]+=2; deg[j]+=2; deg[k]+=2;
__global__ void scatter_kernel(const int* __restrict__ faces,
                               const float* __restrict__ d,
                               float* __restrict__ nn,
                               float* __restrict__ deg) {
    int idx = blockIdx.x * blockDim.x + threadIdx.x;
    if (idx >= BATCH * NFACES) return;
    int b = idx / NFACES;

    const int* fp = faces + (size_t)idx * 3;
    int i = fp[0], j = fp[1], k = fp[2];

    const float* db  = d   + (size_t)b * NPOINT * 3;
    float*       nnb = nn  + (size_t)b * NPOINT * 3;
    float*       dgb = deg + (size_t)b * NPOINT;

    float ix = db[3*i+0], iy = db[3*i+1], iz = db[3*i+2];
    float jx = db[3*j+0], jy = db[3*j+1], jz = db[3*j+2];
    float kx = db[3*k+0], ky = db[3*k+1], kz = db[3*k+2];

    atomicAdd(&nnb[3*i+0], jx + kx);
    atomicAdd(&nnb[3*i+1], jy + ky);
    atomicAdd(&nnb[3*i+2], jz + kz);
    atomicAdd(&nnb[3*j+0], ix + kx);
    atomicAdd(&nnb[3*j+1], iy + ky);
    atomicAdd(&nnb[3*j+2], iz + kz);
    atomicAdd(&nnb[3*k+0], ix + jx);
    atomicAdd(&nnb[3*k+1], iy + jy);
    atomicAdd(&nnb[3*k+2], iz + jz);
    atomicAdd(&dgb[i], 2.0f);
    atomicAdd(&dgb[j], 2.0f);
    atomicAdd(&dgb[k], 2.0f);
}

// -------------------------------------------------------------- reduce ----
__global__ void reduce_kernel(const float* __restrict__ d,
                              const float* __restrict__ nn,
                              const float* __restrict__ deg,
                              float* __restrict__ out) {
    int idx    = blockIdx.x * blockDim.x + threadIdx.x;
    int stride = gridDim.x * blockDim.x;
    float s = 0.f;
    for (int v = idx; v < BATCH * NPOINT; v += stride) {
        float g   = fmaxf(deg[v], 1.0f);
        float inv = 1.0f / g;
        s += fabsf(nn[3*v+0] * inv - d[3*v+0])
           + fabsf(nn[3*v+1] * inv - d[3*v+1])
           + fabsf(nn[3*v+2] * inv - d[3*v+2]);
    }
    // wave64 butterfly reduce
    #pragma unroll
    for (int off = 32; off > 0; off >>= 1) s += __shfl_down(s, off, 64);

    __shared__ float ls[4];
    int lane = threadIdx.x & 63, wid = threadIdx.x >> 6;
    if (lane == 0) ls[wid] = s;
    __syncthreads();
    if (threadIdx.x == 0) {
        float t = ls[0] + ls[1] + ls[2] + ls[3];
        atomicAdd(out, t * (1.0f / (float)(BATCH * NPOINT * 3)));
    }
}

// -------------------------------------------------------------- launch ----
extern "C" void kernel_launch(void* const* d_in, const int* in_sizes, int n_in,
                              void* d_out, int out_size, void* d_ws, size_t ws_size,
                              hipStream_t stream) {
    const float* v1    = (const float*)d_in[0];
    const float* v2    = (const float*)d_in[1];
    const int*   faces = (const int*)d_in[2];
    float*       out   = (float*)d_out;

    const size_t nElem = (size_t)BATCH * NPOINT * 3;   // 1.2M floats
    char*  ws  = (char*)d_ws;
    float* d   = (float*)ws;                               // 4.8 MB
    float* nn  = (float*)(ws + nElem * sizeof(float));     // 4.8 MB
    float* deg = (float*)(ws + 2 * nElem * sizeof(float)); // 1.6 MB (contiguous after nn)

    // zero accumulators + output every call (harness doesn't re-poison)
    hipMemsetAsync(nn, 0, (nElem + (size_t)BATCH * NPOINT) * sizeof(float), stream);
    hipMemsetAsync(out, 0, sizeof(float), stream);

    diff_kernel<<<2048, 256, 0, stream>>>(v1, v2, d, (int)nElem);

    int nf = BATCH * NFACES;
    scatter_kernel<<<(nf + 255) / 256, 256, 0, stream>>>(faces, d, nn, deg);

    int nv = BATCH * NPOINT;
    reduce_kernel<<<(nv + 255) / 256, 256, 0, stream>>>(d, nn, deg, out);
}